// Round 4
// baseline (1647.879 us; speedup 1.0000x reference)
//
#include <hip/hip_runtime.h>
#include <hip/hip_bf16.h>

using bf16 = __hip_bfloat16;

using frag_ab = __attribute__((ext_vector_type(8))) short;  // 8 bf16 = 4 VGPRs
using frag_cd = __attribute__((ext_vector_type(4))) float;  // 4 fp32 acc

__device__ __forceinline__ unsigned short f2bu(float f) {
    bf16 h = __float2bfloat16(f);
    return *(unsigned short*)&h;
}

__device__ __forceinline__ void st_c(float* p, float v) { *p = v; }
__device__ __forceinline__ void st_c(bf16* p, float v)  { *p = __float2bfloat16(v); }

// 16B-per-lane async global->LDS. Per-wave LDS dest = uniform base + lane*16.
__device__ __forceinline__ void load16(const bf16* g, bf16* l) {
    __builtin_amdgcn_global_load_lds(
        (const __attribute__((address_space(1))) unsigned int*)g,
        (__attribute__((address_space(3))) unsigned int*)l,
        16, 0, 0);
}

// ---------------------------------------------------------------------------
// Round 4: 2-slot / 64KiB double-buffer GEMM, 2 blocks per CU.
// Rounds 1-3 proved the 128KiB 8-phase schedule pins occupancy at 1 block/CU
// and its intra-block pipeline never materializes (MfmaUtil stuck 26-31%).
// This version keeps the 256-wide tile economics (384B LDS-read/MFMA) but
// uses the guide's minimum T3 recipe with a 2-slot BK=32 ring:
//   stage(next slot) -> ds_read cur -> [auto lgkm] -> 32 MFMA -> vmcnt(0)
//   -> ONE barrier.
// Race-freedom: reads of slot s complete (dataflow lgkm) before each wave's
// MFMA, which precedes its barrier; restage of s is issued after that
// barrier. Staged data is drained by vmcnt(0)+barrier before its reads.
// 64KiB (TM=256) / 48KiB (TM=128) => 2 blocks/CU co-resident; the two
// unsynchronized blocks interleave on the matrix/LDS/L2 pipes (m114
// mechanism) and hide each other's serial sections.
// WM = per-wave M rows (wave grid 2Mx4N of WMx64): TM=2*WM, TN=256.
// Bank swizzle: rotate chunk (quad + (row>>1))&3 -- 0-conflict (r2-verified).
// ---------------------------------------------------------------------------
template <typename TC, bool HAS_BIAS, bool MASK, int WM>
__global__ __launch_bounds__(512, 4)
void gemm_db(const bf16* __restrict__ A, const bf16* __restrict__ B,
             const float* __restrict__ bias, const int* __restrict__ mask,
             TC* __restrict__ C, int K, int lda, int ldb, int ldc,
             long sA, long sB, long sC, long sM, float scale)
{
    constexpr int TM   = 2 * WM;            // 256 or 128
    constexpr int AF   = WM / 16;           // A fragments per wave (8 or 4)
    constexpr int SLOT = TM * 32 + 8192;    // shorts: A[TM][32] + B[256][32]
    __shared__ short lds[2 * SLOT];

    const int bz = blockIdx.z;
    const bf16* Ab = A + (long)bz * sA;
    const bf16* Bb = B + (long)bz * sB;
    TC* Cb = C + (long)bz * sC;
    const int* maskb = MASK ? (mask + (long)bz * sM) : nullptr;

    const int t    = threadIdx.x;
    const int wid  = t >> 6;
    const int lane = t & 63;
    const int m0 = blockIdx.x * TM;
    const int n0 = blockIdx.y * 256;
    const int wr = wid >> 2;       // 0..1  (M wave)
    const int wc = wid & 3;        // 0..3  (N wave)
    const int lrow = lane & 15;
    const int quad = lane >> 4;

    // reader-side swizzled 16B chunk: rotate by (row>>1)&3 (row ≡ lrow mod 16)
    const int rco   = ((quad + ((lrow >> 1) & 3)) & 3) * 8;   // shorts
    const int a_off = wr * (WM * 32) + lrow * 32 + rco;       // + i*512
    const int b_off = TM * 32 + wc * 2048 + lrow * 32 + rco;  // + j*512

    // staging: each load16 covers 16 LDS rows (1024B linear); lane l -> row
    // l>>2, chunk l&3; global chunk pre-rotated: (c - (row>>1)) & 3.
    // (wave row bases are multiples of 8 => (lane>>3)&3 == (srow>>1)&3.)
    const int srowA = wid * (TM / 8) + (lane >> 2);
    const int srowB = wid * 32 + (lane >> 2);
    const int gk    = (((lane & 3) - (lane >> 3)) & 3) * 8;
    const bf16* sA0 = Ab + (long)(m0 + srowA) * lda + gk;
    const bf16* sA1 = sA0 + (long)16 * lda;            // TM==256 only
    const bf16* sB0 = Bb + (long)(n0 + srowB) * ldb + gk;
    const bf16* sB1 = sB0 + (long)16 * ldb;
    const int dstA = wid * (TM * 4) + lane * 8;        // shorts
    const int dstB = TM * 32 + wid * 1024 + lane * 8;

    frag_cd acc[AF][4] = {};

    auto stage = [&](int slot, int k0) {
        const int sb = slot * SLOT;
        load16(sA0 + k0, (bf16*)&lds[sb + dstA]);
        if constexpr (TM == 256)
            load16(sA1 + k0, (bf16*)&lds[sb + dstA + 512]);
        load16(sB0 + k0, (bf16*)&lds[sb + dstB]);
        load16(sB1 + k0, (bf16*)&lds[sb + dstB + 512]);
    };

    // prologue: fill slot 0
    stage(0, 0);
    asm volatile("s_waitcnt vmcnt(0)" ::: "memory");
    __builtin_amdgcn_s_barrier();

    int cur = 0;
    for (int k0 = 0; k0 < K; k0 += 32) {
        if (k0 + 32 < K) stage(cur ^ 1, k0 + 32);   // prefetch next slot

        frag_ab af[AF], bfv[4];
#pragma unroll
        for (int i = 0; i < AF; ++i)
            af[i] = *(const frag_ab*)&lds[cur * SLOT + a_off + i * 512];
#pragma unroll
        for (int j = 0; j < 4; ++j)
            bfv[j] = *(const frag_ab*)&lds[cur * SLOT + b_off + j * 512];
        __builtin_amdgcn_sched_barrier(0);

        __builtin_amdgcn_s_setprio(1);
#pragma unroll
        for (int i = 0; i < AF; ++i)
#pragma unroll
            for (int j = 0; j < 4; ++j)
                acc[i][j] = __builtin_amdgcn_mfma_f32_16x16x32_bf16(
                    af[i], bfv[j], acc[i][j], 0, 0, 0);
        __builtin_amdgcn_s_setprio(0);
        __builtin_amdgcn_sched_barrier(0);

        asm volatile("s_waitcnt vmcnt(0)" ::: "memory");  // next slot landed
        __builtin_amdgcn_s_barrier();
        cur ^= 1;
    }

    // epilogue: C/D layout col=lane&15, row=quad*4+reg  [m89-verified]
#pragma unroll
    for (int j = 0; j < 4; ++j) {
        const int col = n0 + wc * 64 + j * 16 + lrow;
        const float bv = HAS_BIAS ? bias[col] : 0.0f;
        const bool msk = MASK ? (maskb[col] != 0) : false;
#pragma unroll
        for (int ai = 0; ai < AF; ++ai) {
            const int rbase = m0 + wr * WM + ai * 16 + quad * 4;
#pragma unroll
            for (int r = 0; r < 4; ++r) {
                float v = acc[ai][j][r] * scale + bv;
                if (MASK && msk) v = -INFINITY;
                st_c(&Cb[(long)(rbase + r) * ldc + col], v);
            }
        }
    }
}

// fp32 X[b][s][h] -> bf16 Xb[b][s][h] and bf16 XT[b][h][s], 64x64 tiles.
__global__ __launch_bounds__(256)
void convert_transpose(const float* __restrict__ X, bf16* __restrict__ Xb,
                       bf16* __restrict__ XT, int S, int H)
{
    __shared__ unsigned short tile[64][72];
    const int b = blockIdx.z;
    const float* Xp = X + (long)b * S * H;
    bf16* Xbp = Xb + (long)b * S * H;
    bf16* XTp = XT + (long)b * H * S;
    const int h0 = blockIdx.x * 64, s0 = blockIdx.y * 64;
    const int t = threadIdx.x;
    const int r  = t >> 4;
    const int c4 = (t & 15) * 4;

#pragma unroll
    for (int p = 0; p < 4; ++p) {
        const int row = r + p * 16;
        const float4 v = *(const float4*)&Xp[(long)(s0 + row) * H + h0 + c4];
        ushort4 u;
        u.x = f2bu(v.x); u.y = f2bu(v.y); u.z = f2bu(v.z); u.w = f2bu(v.w);
        *(ushort4*)&tile[row][c4] = u;
        *(ushort4*)&Xbp[(long)(s0 + row) * H + h0 + c4] = u;
    }
    __syncthreads();
#pragma unroll
    for (int p = 0; p < 4; ++p) {
        const int hrow = r + p * 16;
        ushort4 u;
        u.x = tile[c4 + 0][hrow];
        u.y = tile[c4 + 1][hrow];
        u.z = tile[c4 + 2][hrow];
        u.w = tile[c4 + 3][hrow];
        *(ushort4*)&XTp[(long)(h0 + hrow) * S + s0 + c4] = u;
    }
}

// both weight matrices -> bf16, contiguous out [2*H*H]
__global__ __launch_bounds__(256)
void convert_w2(const float* __restrict__ wa, const float* __restrict__ wb,
                bf16* __restrict__ out, int n4each)
{
    const int i = blockIdx.x * 256 + threadIdx.x;
    const bool second = i >= n4each;
    const float* src = second ? wb : wa;
    const int j = second ? i - n4each : i;
    const float4 v = ((const float4*)src)[j];
    ushort4 u;
    u.x = f2bu(v.x); u.y = f2bu(v.y); u.z = f2bu(v.z); u.w = f2bu(v.w);
    ((ushort4*)out)[i] = u;
}

__global__ __launch_bounds__(256)
void pack_bias(const float* __restrict__ qb, const float* __restrict__ kb,
               float* __restrict__ out, int H)
{
    const int i = blockIdx.x * 256 + threadIdx.x;
    out[i] = (i < H) ? qb[i] : kb[i - H];
}

// In-place masked softmax over rows (Slen=2048 bf16). Mask pre-applied as -inf.
__global__ __launch_bounds__(256)
void softmax_kernel(bf16* __restrict__ Smat, int Slen)
{
    const int row = blockIdx.x;
    bf16* srow = Smat + (long)row * Slen;

    const int t    = threadIdx.x;
    const int lane = t & 63;
    const int wid  = t >> 6;

    ushort4 u0 = ((const ushort4*)srow)[t * 2];
    ushort4 u1 = ((const ushort4*)srow)[t * 2 + 1];

    float vals[8];
    {
        const unsigned short us[8] = {u0.x, u0.y, u0.z, u0.w, u1.x, u1.y, u1.z, u1.w};
#pragma unroll
        for (int i = 0; i < 8; ++i) {
            unsigned int w = (unsigned int)us[i] << 16;
            vals[i] = *(float*)&w;
        }
    }

    float mx = vals[0];
#pragma unroll
    for (int i = 1; i < 8; ++i) mx = fmaxf(mx, vals[i]);

    __shared__ float red[4];
#pragma unroll
    for (int o = 32; o > 0; o >>= 1) mx = fmaxf(mx, __shfl_xor(mx, o, 64));
    if (lane == 0) red[wid] = mx;
    __syncthreads();
    mx = fmaxf(fmaxf(red[0], red[1]), fmaxf(red[2], red[3]));
    __syncthreads();

    float sum = 0.0f;
#pragma unroll
    for (int i = 0; i < 8; ++i) {
        const float e = __expf(vals[i] - mx);   // exp(-inf - mx) = 0
        vals[i] = e;
        sum += e;
    }
#pragma unroll
    for (int o = 32; o > 0; o >>= 1) sum += __shfl_xor(sum, o, 64);
    if (lane == 0) red[wid] = sum;
    __syncthreads();
    sum = red[0] + red[1] + red[2] + red[3];

    const float inv = 1.0f / sum;
    ushort4 o0, o1;
    o0.x = f2bu(vals[0] * inv); o0.y = f2bu(vals[1] * inv);
    o0.z = f2bu(vals[2] * inv); o0.w = f2bu(vals[3] * inv);
    o1.x = f2bu(vals[4] * inv); o1.y = f2bu(vals[5] * inv);
    o1.z = f2bu(vals[6] * inv); o1.w = f2bu(vals[7] * inv);
    ((ushort4*)srow)[t * 2]     = o0;
    ((ushort4*)srow)[t * 2 + 1] = o1;
}

extern "C" void kernel_launch(void* const* d_in, const int* in_sizes, int n_in,
                              void* d_out, int out_size, void* d_ws, size_t ws_size,
                              hipStream_t stream)
{
    const float* hidden = (const float*)d_in[0];
    const int*   mask   = (const int*)d_in[1];
    const float* Wq_w   = (const float*)d_in[2];
    const float* Wq_b   = (const float*)d_in[3];
    const float* Wk_w   = (const float*)d_in[4];
    const float* Wk_b   = (const float*)d_in[5];
    float* out = (float*)d_out;

    const int B = 8, S = 2048, H = 1024;
    const int M = B * S;               // 16384
    const long MH = (long)M * H;       // 16.7M elems

    // ws (bf16 elems): QK[M][2H] (67MB) | XbT (33.5MB) | Sb (67MB)
    // Xb + Wb (stacked weights) + packed bias aliased inside Sb (dead before scores).
    bf16* QK  = (bf16*)d_ws;
    bf16* XbT = QK + MH * 2;
    bf16* Sb  = XbT + MH;
    bf16* Xb  = Sb;                    // aliased
    bf16* Wb  = Xb + MH;               // [2H][H] = Wq stacked on Wk
    float* biasP = (float*)(Wb + 2L * H * H);  // 2048 floats

    const dim3 blk(256);
    const dim3 blk512(512);

    convert_transpose<<<dim3(H / 64, S / 64, B), blk, 0, stream>>>(hidden, Xb, XbT, S, H);
    convert_w2<<<dim3(2 * H * H / 1024), blk, 0, stream>>>(Wq_w, Wk_w, Wb, H * H / 4);
    pack_bias<<<dim3(2 * H / 256), blk, 0, stream>>>(Wq_b, Wk_b, biasP, H);

    // QK = Xb @ [Wq;Wk]^T + [bq;bk]  : 16384 x 2048, K=1024. 512 blocks, 2/CU.
    gemm_db<bf16, true, false, 128><<<dim3(M / 256, 2 * H / 256, 1), blk512, 0, stream>>>(
        Xb, Wb, biasP, nullptr, QK, H, H, H, 2 * H, 0, 0, 0, 0, 1.0f);

    // Scores_b = (Q_b @ K_b^T)/32 : 2048x2048 x8, K=1024. 512 blocks, 2/CU.
    gemm_db<bf16, false, true, 128><<<dim3(S / 256, S / 256, B), blk512, 0, stream>>>(
        QK, QK + H, nullptr, mask, Sb, H, 2 * H, 2 * H, S,
        (long)S * 2 * H, (long)S * 2 * H, (long)S * S, S, 1.0f / 32.0f);

    // softmax in place (mask already -inf)
    softmax_kernel<<<dim3(B * S), blk, 0, stream>>>(Sb, S);

    // Out_b = P_b @ X_b : 2048x1024 x8, K=2048. TM=128 -> 512 blocks, 2/CU.
    gemm_db<float, false, false, 64><<<dim3(S / 128, H / 256, B), blk512, 0, stream>>>(
        Sb, XbT, nullptr, nullptr, out, S, S, S, H,
        (long)S * S, (long)H * S, (long)S * H, 0, 1.0f);
}

// Round 5
// 383.023 us; speedup vs baseline: 4.3023x; 4.3023x over previous
//
#include <hip/hip_runtime.h>
#include <hip/hip_bf16.h>

using bf16 = __hip_bfloat16;

using frag_ab = __attribute__((ext_vector_type(8))) short;  // 8 bf16 = 4 VGPRs
using frag_cd = __attribute__((ext_vector_type(4))) float;  // 4 fp32 acc

__device__ __forceinline__ unsigned short f2bu(float f) {
    bf16 h = __float2bfloat16(f);
    return *(unsigned short*)&h;
}

__device__ __forceinline__ void st_c(float* p, float v) { *p = v; }
__device__ __forceinline__ void st_c(bf16* p, float v)  { *p = __float2bfloat16(v); }

// 16B-per-lane async global->LDS. Per-wave LDS dest = uniform base + lane*16.
__device__ __forceinline__ void load16(const bf16* g, bf16* l) {
    __builtin_amdgcn_global_load_lds(
        (const __attribute__((address_space(1))) unsigned int*)g,
        (__attribute__((address_space(3))) unsigned int*)l,
        16, 0, 0);
}

// ---------------------------------------------------------------------------
// 256x256 8-phase GEMM, round 5: round-3 ring with sched_barrier(0) fences
// REMOVED (m141: sched_barrier(0) order-pinning costs ~40% -- it forbade the
// compiler from interleaving next-phase ds_read issue with the MFMA cluster
// and from counted-lgkm pipelining). Memory ops stay pinned to their phase by
// empty asm memory clobbers at the same points, so the ring's race-freedom
// argument is unchanged from r3 (which passed):
//  - 4 slots, slot s read at phases 2s,2s+1 (A read-ahead 1 phase, B per-slot
//    double-buffered in regs), restaged at phases 2s+2,2s+3.
//  - vmcnt(6) before the end-barrier of even phases drains the slot staged 4
//    phases earlier, one barrier before its read-issue.
//  - reader swizzle rotate chunk (quad + (row>>1))&3: 0 conflicts (r2-meas).
// launch_bounds(512,2): 128 arch VGPR + 128 acc AGPR fits 8 waves/CU.
// (r4 lesson: (512,4) => 128 TOTAL regs => acc spills to scratch, 1.4GB/2.3GB
// scratch traffic per dispatch. Never again.)
// ---------------------------------------------------------------------------
template <typename TC, bool HAS_BIAS, bool MASK>
__global__ __launch_bounds__(512, 2)
void gemm8p(const bf16* __restrict__ A, const bf16* __restrict__ B,
            const float* __restrict__ bias, const int* __restrict__ mask,
            TC* __restrict__ C, int K, int lda, int ldb, int ldc,
            long sA, long sB, long sC, long sM, float scale)
{
    __shared__ short lds[65536];   // 4 slots x 16384 shorts = 128 KiB

    const int bz = blockIdx.z;
    const bf16* Ab = A + (long)bz * sA;
    const bf16* Bb = B + (long)bz * sB;
    TC* Cb = C + (long)bz * sC;
    const int* maskb = MASK ? (mask + (long)bz * sM) : nullptr;

    const int t    = threadIdx.x;
    const int wid  = t >> 6;
    const int lane = t & 63;
    const int m0 = blockIdx.x * 256;
    const int n0 = blockIdx.y * 256;
    const int wr = wid >> 2;       // 0..1  (M wave)
    const int wc = wid & 3;        // 0..3  (N wave)
    const int lrow = lane & 15;
    const int quad = lane >> 4;

    // reader-side swizzled 16B chunk: rotate by (row>>1)&3 (row ≡ lrow mod 16)
    const int rco   = ((quad + ((lrow >> 1) & 3)) & 3) * 8;   // shorts
    const int a_off = wr * 4096 + lrow * 32 + rco;   // + qm*2048 + i*512
    const int b_off = wc * 2048 + lrow * 32 + rco;   // + j*512 (B part +8192)

    // staging: each load16 covers 16 LDS rows (1024B linear); lane l -> row
    // l>>2, chunk l&3; global chunk pre-rotated: (c - (row>>1)) & 3.
    const int srow = wid * 32 + (lane >> 2);
    const int gk   = (((lane & 3) - (lane >> 3)) & 3) * 8;
    const bf16* srcA0 = Ab + (long)(m0 + srow) * lda + gk;
    const bf16* srcA1 = Ab + (long)(m0 + srow + 16) * lda + gk;
    const bf16* srcB0 = Bb + (long)(n0 + srow) * ldb + gk;
    const bf16* srcB1 = Bb + (long)(n0 + srow + 16) * ldb + gk;
    const int dst0 = wid * 1024 + lane * 8;          // shorts

    frag_cd acc[8][4] = {};
    frag_ab A0[4], A1[4], B0[4], B1[4];   // double-buffered fragments

#define STG(SLOT, PART, K0)                                                     \
    do {                                                                        \
        load16((PART ? srcB0 : srcA0) + (K0),                                   \
               (bf16*)&lds[(SLOT) * 16384 + (PART) * 8192 + dst0]);             \
        load16((PART ? srcB1 : srcA1) + (K0),                                   \
               (bf16*)&lds[(SLOT) * 16384 + (PART) * 8192 + dst0 + 512]);       \
    } while (0)

#define LOADA(DST, SLOT, QM)                                                    \
    do {                                                                        \
        _Pragma("unroll")                                                       \
        for (int i_ = 0; i_ < 4; ++i_)                                          \
            DST[i_] = *(const frag_ab*)&lds[(SLOT) * 16384 + a_off +            \
                                            (QM) * 2048 + i_ * 512];            \
    } while (0)

#define LOADB(DST, SLOT)                                                        \
    do {                                                                        \
        _Pragma("unroll")                                                       \
        for (int j_ = 0; j_ < 4; ++j_)                                          \
            DST[j_] = *(const frag_ab*)&lds[(SLOT) * 16384 + 8192 + b_off +     \
                                            j_ * 512];                          \
    } while (0)

#define MFMA16(AR, BR, QM)                                                      \
    do {                                                                        \
        _Pragma("unroll")                                                       \
        for (int i_ = 0; i_ < 4; ++i_)                                          \
            _Pragma("unroll")                                                   \
            for (int j_ = 0; j_ < 4; ++j_)                                      \
                acc[(QM) * 4 + i_][j_] = __builtin_amdgcn_mfma_f32_16x16x32_bf16( \
                    AR[i_], BR[j_], acc[(QM) * 4 + i_][j_], 0, 0, 0);           \
    } while (0)

#define VMW(N)                                                                  \
    do {                                                                        \
        if ((N) == 6)      asm volatile("s_waitcnt vmcnt(6)" ::: "memory");     \
        else if ((N) == 4) asm volatile("s_waitcnt vmcnt(4)" ::: "memory");     \
        else if ((N) == 0) asm volatile("s_waitcnt vmcnt(0)" ::: "memory");     \
    } while (0)

// Phase: issue batch p+1 reads (ISSUE: 1=A only, 2=A+B) + stage; MFMA cluster
// p (compiler-counted lgkm; MFMA free to interleave with the issue stream);
// optional vmcnt; end barrier. Mem ops pinned to the phase by the clobbers.
#define PH(AR, BR, QM, ISSUE, NSLOT, NAR, NBR, NQM, DO_STG, SSLOT, SPART, SK0, VMN) \
    do {                                                                        \
        if ((ISSUE) >= 1) LOADA(NAR, NSLOT, NQM);                               \
        if ((ISSUE) == 2) LOADB(NBR, NSLOT);                                    \
        if (DO_STG) STG(SSLOT, SPART, SK0);                                     \
        asm volatile("" ::: "memory");                                          \
        __builtin_amdgcn_s_setprio(1);                                          \
        MFMA16(AR, BR, QM);                                                     \
        __builtin_amdgcn_s_setprio(0);                                          \
        VMW(VMN);                                                               \
        asm volatile("" ::: "memory");                                          \
        __builtin_amdgcn_s_barrier();                                           \
        asm volatile("" ::: "memory");                                          \
    } while (0)

    // prologue: slot0 = tile0 ks0, slot1 = tile0 ks1, slot2 = tile1 ks0
    STG(0, 0, 0);  STG(0, 1, 0);
    STG(1, 0, 32); STG(1, 1, 32);
    STG(2, 0, 64); STG(2, 1, 64);
    asm volatile("s_waitcnt vmcnt(8)" ::: "memory");   // slot0 landed
    __builtin_amdgcn_s_barrier();
    asm volatile("" ::: "memory");
    LOADA(A0, 0, 0);      // batch 0 (cluster 0)
    LOADB(B0, 0);

    const int NI = K >> 7;   // 128 K per iteration (2 K-tiles); NI >= 2 here
    for (int it = 0; it < NI - 1; ++it) {
        const int kb = it << 7;
        //  cur    QM IS NS nxt      NQ STG SS SP SK0      VM
        PH(A0, B0, 0, 1, 0, A1, B1, 1, 1, 3, 0, kb + 96,   6);
        PH(A1, B0, 1, 2, 1, A0, B1, 0, 1, 3, 1, kb + 96,  -1);
        PH(A0, B1, 0, 1, 1, A1, B0, 1, 1, 0, 0, kb + 128,  6);
        PH(A1, B1, 1, 2, 2, A0, B0, 0, 1, 0, 1, kb + 128, -1);
        PH(A0, B0, 0, 1, 2, A1, B1, 1, 1, 1, 0, kb + 160,  6);
        PH(A1, B0, 1, 2, 3, A0, B1, 0, 1, 1, 1, kb + 160, -1);
        PH(A0, B1, 0, 1, 3, A1, B0, 1, 1, 2, 0, kb + 192,  6);
        PH(A1, B1, 1, 2, 0, A0, B0, 0, 1, 2, 1, kb + 192, -1);
    }
    {   // peeled last iteration: only slot3 (ks1 of last tile) still staged
        const int kb = (NI - 1) << 7;
        PH(A0, B0, 0, 1, 0, A1, B1, 1, 1, 3, 0, kb + 96,   6);
        PH(A1, B0, 1, 2, 1, A0, B1, 0, 1, 3, 1, kb + 96,  -1);
        PH(A0, B1, 0, 1, 1, A1, B0, 1, 0, 0, 0, 0,         4);
        PH(A1, B1, 1, 2, 2, A0, B0, 0, 0, 0, 0, 0,        -1);
        PH(A0, B0, 0, 1, 2, A1, B1, 1, 0, 0, 0, 0,         0);
        PH(A1, B0, 1, 2, 3, A0, B1, 0, 0, 0, 0, 0,        -1);
        PH(A0, B1, 0, 1, 3, A1, B0, 1, 0, 0, 0, 0,        -1);
        PH(A1, B1, 1, 0, 0, A0, B0, 0, 0, 0, 0, 0,        -1);
    }
#undef PH
#undef VMW
#undef MFMA16
#undef LOADB
#undef LOADA
#undef STG

    // epilogue: C/D layout col=lane&15, row=quad*4+reg  [m89-verified]
#pragma unroll
    for (int j = 0; j < 4; ++j) {
        const int col = n0 + wc * 64 + j * 16 + lrow;
        const float bv = HAS_BIAS ? bias[col] : 0.0f;
        const bool msk = MASK ? (maskb[col] != 0) : false;
#pragma unroll
        for (int ai = 0; ai < 8; ++ai) {
            const int rbase = m0 + wr * 128 + ai * 16 + quad * 4;
#pragma unroll
            for (int r = 0; r < 4; ++r) {
                float v = acc[ai][j][r] * scale + bv;
                if (MASK && msk) v = -INFINITY;
                st_c(&Cb[(long)(rbase + r) * ldc + col], v);
            }
        }
    }
}

// fp32 X[b][s][h] -> bf16 Xb[b][s][h] and bf16 XT[b][h][s], 64x64 tiles.
__global__ __launch_bounds__(256)
void convert_transpose(const float* __restrict__ X, bf16* __restrict__ Xb,
                       bf16* __restrict__ XT, int S, int H)
{
    __shared__ unsigned short tile[64][72];
    const int b = blockIdx.z;
    const float* Xp = X + (long)b * S * H;
    bf16* Xbp = Xb + (long)b * S * H;
    bf16* XTp = XT + (long)b * H * S;
    const int h0 = blockIdx.x * 64, s0 = blockIdx.y * 64;
    const int t = threadIdx.x;
    const int r  = t >> 4;
    const int c4 = (t & 15) * 4;

#pragma unroll
    for (int p = 0; p < 4; ++p) {
        const int row = r + p * 16;
        const float4 v = *(const float4*)&Xp[(long)(s0 + row) * H + h0 + c4];
        ushort4 u;
        u.x = f2bu(v.x); u.y = f2bu(v.y); u.z = f2bu(v.z); u.w = f2bu(v.w);
        *(ushort4*)&tile[row][c4] = u;
        *(ushort4*)&Xbp[(long)(s0 + row) * H + h0 + c4] = u;
    }
    __syncthreads();
#pragma unroll
    for (int p = 0; p < 4; ++p) {
        const int hrow = r + p * 16;
        ushort4 u;
        u.x = tile[c4 + 0][hrow];
        u.y = tile[c4 + 1][hrow];
        u.z = tile[c4 + 2][hrow];
        u.w = tile[c4 + 3][hrow];
        *(ushort4*)&XTp[(long)(h0 + hrow) * S + s0 + c4] = u;
    }
}

// both weight matrices -> bf16, contiguous out [2*H*H]
__global__ __launch_bounds__(256)
void convert_w2(const float* __restrict__ wa, const float* __restrict__ wb,
                bf16* __restrict__ out, int n4each)
{
    const int i = blockIdx.x * 256 + threadIdx.x;
    const bool second = i >= n4each;
    const float* src = second ? wb : wa;
    const int j = second ? i - n4each : i;
    const float4 v = ((const float4*)src)[j];
    ushort4 u;
    u.x = f2bu(v.x); u.y = f2bu(v.y); u.z = f2bu(v.z); u.w = f2bu(v.w);
    ((ushort4*)out)[i] = u;
}

__global__ __launch_bounds__(256)
void pack_bias(const float* __restrict__ qb, const float* __restrict__ kb,
               float* __restrict__ out, int H)
{
    const int i = blockIdx.x * 256 + threadIdx.x;
    out[i] = (i < H) ? qb[i] : kb[i - H];
}

// In-place masked softmax over rows (Slen=2048 bf16). Mask pre-applied as -inf.
__global__ __launch_bounds__(256)
void softmax_kernel(bf16* __restrict__ Smat, int Slen)
{
    const int row = blockIdx.x;
    bf16* srow = Smat + (long)row * Slen;

    const int t    = threadIdx.x;
    const int lane = t & 63;
    const int wid  = t >> 6;

    ushort4 u0 = ((const ushort4*)srow)[t * 2];
    ushort4 u1 = ((const ushort4*)srow)[t * 2 + 1];

    float vals[8];
    {
        const unsigned short us[8] = {u0.x, u0.y, u0.z, u0.w, u1.x, u1.y, u1.z, u1.w};
#pragma unroll
        for (int i = 0; i < 8; ++i) {
            unsigned int w = (unsigned int)us[i] << 16;
            vals[i] = *(float*)&w;
        }
    }

    float mx = vals[0];
#pragma unroll
    for (int i = 1; i < 8; ++i) mx = fmaxf(mx, vals[i]);

    __shared__ float red[4];
#pragma unroll
    for (int o = 32; o > 0; o >>= 1) mx = fmaxf(mx, __shfl_xor(mx, o, 64));
    if (lane == 0) red[wid] = mx;
    __syncthreads();
    mx = fmaxf(fmaxf(red[0], red[1]), fmaxf(red[2], red[3]));
    __syncthreads();

    float sum = 0.0f;
#pragma unroll
    for (int i = 0; i < 8; ++i) {
        const float e = __expf(vals[i] - mx);   // exp(-inf - mx) = 0
        vals[i] = e;
        sum += e;
    }
#pragma unroll
    for (int o = 32; o > 0; o >>= 1) sum += __shfl_xor(sum, o, 64);
    if (lane == 0) red[wid] = sum;
    __syncthreads();
    sum = red[0] + red[1] + red[2] + red[3];

    const float inv = 1.0f / sum;
    ushort4 o0, o1;
    o0.x = f2bu(vals[0] * inv); o0.y = f2bu(vals[1] * inv);
    o0.z = f2bu(vals[2] * inv); o0.w = f2bu(vals[3] * inv);
    o1.x = f2bu(vals[4] * inv); o1.y = f2bu(vals[5] * inv);
    o1.z = f2bu(vals[6] * inv); o1.w = f2bu(vals[7] * inv);
    ((ushort4*)srow)[t * 2]     = o0;
    ((ushort4*)srow)[t * 2 + 1] = o1;
}

extern "C" void kernel_launch(void* const* d_in, const int* in_sizes, int n_in,
                              void* d_out, int out_size, void* d_ws, size_t ws_size,
                              hipStream_t stream)
{
    const float* hidden = (const float*)d_in[0];
    const int*   mask   = (const int*)d_in[1];
    const float* Wq_w   = (const float*)d_in[2];
    const float* Wq_b   = (const float*)d_in[3];
    const float* Wk_w   = (const float*)d_in[4];
    const float* Wk_b   = (const float*)d_in[5];
    float* out = (float*)d_out;

    const int B = 8, S = 2048, H = 1024;
    const int M = B * S;               // 16384
    const long MH = (long)M * H;       // 16.7M elems

    // ws (bf16 elems): QK[M][2H] (67MB) | XbT (33.5MB) | Sb (67MB)
    // Xb + Wb (stacked weights) + packed bias aliased inside Sb (dead before scores).
    bf16* QK  = (bf16*)d_ws;
    bf16* XbT = QK + MH * 2;
    bf16* Sb  = XbT + MH;
    bf16* Xb  = Sb;                    // aliased
    bf16* Wb  = Xb + MH;               // [2H][H] = Wq stacked on Wk
    float* biasP = (float*)(Wb + 2L * H * H);  // 2048 floats

    const dim3 blk(256);
    const dim3 blk512(512);

    convert_transpose<<<dim3(H / 64, S / 64, B), blk, 0, stream>>>(hidden, Xb, XbT, S, H);
    convert_w2<<<dim3(2 * H * H / 1024), blk, 0, stream>>>(Wq_w, Wk_w, Wb, H * H / 4);
    pack_bias<<<dim3(2 * H / 256), blk, 0, stream>>>(Wq_b, Wk_b, biasP, H);

    // QK = Xb @ [Wq;Wk]^T + [bq;bk]   (merged, N = 2H) : 16384 x 2048, K=1024
    gemm8p<bf16, true, false><<<dim3(M / 256, 2 * H / 256, 1), blk512, 0, stream>>>(
        Xb, Wb, biasP, nullptr, QK, H, H, H, 2 * H, 0, 0, 0, 0, 1.0f);

    // Scores_b = (Q_b @ K_b^T)/32, mask applied as -inf in epilogue : 2048x2048, K=1024
    gemm8p<bf16, false, true><<<dim3(S / 256, S / 256, B), blk512, 0, stream>>>(
        QK, QK + H, nullptr, mask, Sb, H, 2 * H, 2 * H, S,
        (long)S * 2 * H, (long)S * 2 * H, (long)S * S, S, 1.0f / 32.0f);

    // softmax in place (mask already -inf)
    softmax_kernel<<<dim3(B * S), blk, 0, stream>>>(Sb, S);

    // Out_b = P_b @ X_b  (B operand = XbT, k-contig) : 2048x1024, K=2048
    gemm8p<float, false, false><<<dim3(S / 256, H / 256, B), blk512, 0, stream>>>(
        Sb, XbT, nullptr, nullptr, out, S, S, S, H,
        (long)S * S, (long)H * S, (long)S * H, 0, 1.0f);
}